// Round 2
// baseline (367.690 us; speedup 1.0000x reference)
//
#include <hip/hip_runtime.h>

#define SPATIAL_SCALE 0.25f
#define PH_ 7
#define PW_ 7
#define NBINS 49
#define NSAMP 196          // 49 bins * 4 samples
#define C_ 256
#define H_ 256
#define W_ 256
#define HW_ (H_ * W_)
#define RES_STRIDE 264     // floats; 264*4=1056B rows (16B aligned), 264%32=8
#define CHUNK 16

// ---------------------------------------------------------------------------
// Transpose NCHW -> NHWC, register 4x4 micro-tiles, float4 both sides, no LDS.
// Block = 256 threads = 4 waves; wave w handles channels c0+4w..+3, lanes
// cover 256 consecutive pixels via float4. Each block covers a full 16-channel
// (64B) output line set, so HBM write-back is full lines.
// ---------------------------------------------------------------------------
__global__ __launch_bounds__(256) void transpose_nchw_nhwc(
    const float* __restrict__ in, float* __restrict__ out) {
  const int b    = blockIdx.z;
  const int p0   = blockIdx.x * 256;   // pixel tile (256 px)
  const int c0   = blockIdx.y * 16;    // channel tile (16 ch)
  const int lane = threadIdx.x & 63;
  const int w    = threadIdx.x >> 6;
  const int p    = p0 + lane * 4;
  const int c    = c0 + w * 4;
  const float* src = in  + (size_t)b * C_ * HW_;
  float*       dst = out + (size_t)b * HW_ * C_;

  const float4 r0 = *(const float4*)(src + (size_t)(c + 0) * HW_ + p);
  const float4 r1 = *(const float4*)(src + (size_t)(c + 1) * HW_ + p);
  const float4 r2 = *(const float4*)(src + (size_t)(c + 2) * HW_ + p);
  const float4 r3 = *(const float4*)(src + (size_t)(c + 3) * HW_ + p);

  *(float4*)(dst + (size_t)(p + 0) * C_ + c) = make_float4(r0.x, r1.x, r2.x, r3.x);
  *(float4*)(dst + (size_t)(p + 1) * C_ + c) = make_float4(r0.y, r1.y, r2.y, r3.y);
  *(float4*)(dst + (size_t)(p + 2) * C_ + c) = make_float4(r0.z, r1.z, r2.z, r3.z);
  *(float4*)(dst + (size_t)(p + 3) * C_ + c) = make_float4(r0.w, r1.w, r2.w, r3.w);
}

// ---------------------------------------------------------------------------
// Shared descriptor computation (phase 1): sample corner offsets + weights.
// ---------------------------------------------------------------------------
template <bool NHWC>
__device__ inline void compute_descriptors(const float* __restrict__ rois,
                                           int r, int t,
                                           int4* d_off, float4* d_w) {
  if (t < NSAMP) {
    const float* rp = rois + r * 6;
    const int   b  = (int)rp[0];
    const float cx = rp[1] * SPATIAL_SCALE - 0.5f;
    const float cy = rp[2] * SPATIAL_SCALE - 0.5f;
    const float rw = rp[3] * SPATIAL_SCALE;
    const float rh = rp[4] * SPATIAL_SCALE;
    const float th = rp[5];                 // CLOCKWISE=False
    float sn, cs;
    sincosf(th, &sn, &cs);
    const float bin_h = rh / (float)PH_;
    const float bin_w = rw / (float)PW_;

    const int s   = t;          // s = bin*4 + sub
    const int bin = s >> 2;
    const int sub = s & 3;
    const int ph  = bin / 7;
    const int pw  = bin - ph * 7;
    const int iy  = sub >> 1;
    const int ix  = sub & 1;

    const float yy = -0.5f * rh + ((float)ph + ((float)iy + 0.5f) * 0.5f) * bin_h;
    const float xx = -0.5f * rw + ((float)pw + ((float)ix + 0.5f) * 0.5f) * bin_w;
    float y = yy * cs - xx * sn + cy;
    float x = yy * sn + xx * cs + cx;

    const bool valid = (y > -1.0f) && (y < (float)H_) &&
                       (x > -1.0f) && (x < (float)W_);
    y = fminf(fmaxf(y, 0.0f), (float)(H_ - 1));
    x = fminf(fmaxf(x, 0.0f), (float)(W_ - 1));
    const int yl = (int)y;
    const int xl = (int)x;
    const int yh = min(yl + 1, H_ - 1);
    const int xh = min(xl + 1, W_ - 1);
    const float ly = y - (float)yl, lx = x - (float)xl;
    const float hy = 1.0f - ly, hx = 1.0f - lx;
    float w11 = hy * hx, w12 = hy * lx, w21 = ly * hx, w22 = ly * lx;
    if (!valid) { w11 = w12 = w21 = w22 = 0.0f; }

    int4 off;
    if (NHWC) {
      off.x = ((b * H_ + yl) * W_ + xl) * C_;
      off.y = ((b * H_ + yl) * W_ + xh) * C_;
      off.z = ((b * H_ + yh) * W_ + xl) * C_;
      off.w = ((b * H_ + yh) * W_ + xh) * C_;
    } else {
      const int base = b * C_ * HW_;
      off.x = base + yl * W_ + xl;
      off.y = base + yl * W_ + xh;
      off.z = base + yh * W_ + xl;
      off.w = base + yh * W_ + xh;
    }
    d_off[s] = off;
    d_w[s]   = make_float4(w11, w12, w21, w22);
  }
}

// ---------------------------------------------------------------------------
// Main NHWC kernel: one block per roi. Wave w handles bin b0+it+w; lanes
// cover all 256 channels via float4 (1 KiB per load instruction). Results
// staged 16 bins at a time in LDS, then written as contiguous-ish runs.
// ---------------------------------------------------------------------------
__global__ __launch_bounds__(256, 4) void roi_align_rotated_nhwc(
    const float* __restrict__ feat, const float* __restrict__ rois,
    float* __restrict__ out) {
  __shared__ int4   d_off[NSAMP];
  __shared__ float4 d_w[NSAMP];
  __shared__ float  res[CHUNK * RES_STRIDE];

  const int r = blockIdx.x;
  const int t = threadIdx.x;

  compute_descriptors<true>(rois, r, t, d_off, d_w);
  __syncthreads();

  const int w  = t >> 6;          // wave id = bin sub-index
  const int c4 = (t & 63) * 4;    // channel base for this lane
  float* outr = out + (size_t)r * (C_ * NBINS);

  for (int chunk = 0; chunk < 3; ++chunk) {
    const int b0 = chunk * CHUNK;
    for (int it = 0; it < CHUNK; it += 4) {
      const int bin = b0 + it + w;
      float4 acc = make_float4(0.f, 0.f, 0.f, 0.f);
#pragma unroll
      for (int sub = 0; sub < 4; ++sub) {
        const int4   o  = d_off[bin * 4 + sub];
        const float4 wt = d_w[bin * 4 + sub];
        const float4 vx = *(const float4*)(feat + o.x + c4);
        const float4 vy = *(const float4*)(feat + o.y + c4);
        const float4 vz = *(const float4*)(feat + o.z + c4);
        const float4 vw = *(const float4*)(feat + o.w + c4);
        acc.x += wt.x * vx.x + wt.y * vy.x + wt.z * vz.x + wt.w * vw.x;
        acc.y += wt.x * vx.y + wt.y * vy.y + wt.z * vz.y + wt.w * vw.y;
        acc.z += wt.x * vx.z + wt.y * vy.z + wt.z * vz.z + wt.w * vw.z;
        acc.w += wt.x * vx.w + wt.y * vy.w + wt.z * vz.w + wt.w * vw.w;
      }
      const int bl = it + w;
      *(float4*)(&res[bl * RES_STRIDE + c4]) =
          make_float4(acc.x * 0.25f, acc.y * 0.25f, acc.z * 0.25f, acc.w * 0.25f);
    }
    __syncthreads();
#pragma unroll 1
    for (int i = t; i < C_ * CHUNK; i += 256) {
      const int cc = i >> 4;       // channel
      const int bb = i & 15;       // bin within chunk
      outr[cc * NBINS + b0 + bb] = res[bb * RES_STRIDE + cc];
    }
    __syncthreads();
  }

  // tail: bin 48 (wave 0 only), direct scattered write
  if (w == 0) {
    const int bin = 48;
    float4 acc = make_float4(0.f, 0.f, 0.f, 0.f);
#pragma unroll
    for (int sub = 0; sub < 4; ++sub) {
      const int4   o  = d_off[bin * 4 + sub];
      const float4 wt = d_w[bin * 4 + sub];
      const float4 vx = *(const float4*)(feat + o.x + c4);
      const float4 vy = *(const float4*)(feat + o.y + c4);
      const float4 vz = *(const float4*)(feat + o.z + c4);
      const float4 vw = *(const float4*)(feat + o.w + c4);
      acc.x += wt.x * vx.x + wt.y * vy.x + wt.z * vz.x + wt.w * vw.x;
      acc.y += wt.x * vx.y + wt.y * vy.y + wt.z * vz.y + wt.w * vw.y;
      acc.z += wt.x * vx.z + wt.y * vy.z + wt.z * vz.z + wt.w * vw.z;
      acc.w += wt.x * vx.w + wt.y * vy.w + wt.z * vz.w + wt.w * vw.w;
    }
    outr[(c4 + 0) * NBINS + bin] = acc.x * 0.25f;
    outr[(c4 + 1) * NBINS + bin] = acc.y * 0.25f;
    outr[(c4 + 2) * NBINS + bin] = acc.z * 0.25f;
    outr[(c4 + 3) * NBINS + bin] = acc.w * 0.25f;
  }
}

// ---------------------------------------------------------------------------
// Fallback: direct NCHW (only if ws too small for the transposed copy).
// ---------------------------------------------------------------------------
__global__ __launch_bounds__(256) void roi_align_rotated_nchw(
    const float* __restrict__ feat, const float* __restrict__ rois,
    float* __restrict__ out) {
  __shared__ int4   d_off[NSAMP];
  __shared__ float4 d_w[NSAMP];
  __shared__ float  res[NBINS * 257];

  const int r = blockIdx.x;
  const int t = threadIdx.x;
  compute_descriptors<false>(rois, r, t, d_off, d_w);
  __syncthreads();

  const int c    = t;
  const int coff = c * HW_;
  for (int bin = 0; bin < NBINS; ++bin) {
    float acc = 0.0f;
#pragma unroll
    for (int sub = 0; sub < 4; ++sub) {
      const int4   o = d_off[bin * 4 + sub];
      const float4 w = d_w[bin * 4 + sub];
      acc += w.x * feat[o.x + coff];
      acc += w.y * feat[o.y + coff];
      acc += w.z * feat[o.z + coff];
      acc += w.w * feat[o.w + coff];
    }
    res[bin * 257 + c] = acc * 0.25f;
  }
  __syncthreads();

  float* outr = out + (size_t)r * (C_ * NBINS);
#pragma unroll 1
  for (int i = t; i < C_ * NBINS; i += 256) {
    const int cc = i / NBINS;
    const int bb = i - cc * NBINS;
    outr[i] = res[bb * 257 + cc];
  }
}

// ---------------------------------------------------------------------------
extern "C" void kernel_launch(void* const* d_in, const int* in_sizes, int n_in,
                              void* d_out, int out_size, void* d_ws, size_t ws_size,
                              hipStream_t stream) {
  const float* feat = (const float*)d_in[0];
  const float* rois = (const float*)d_in[1];
  float* out = (float*)d_out;
  const int n_rois  = in_sizes[1] / 6;
  const int n_batch = in_sizes[0] / (C_ * HW_);

  const size_t need = (size_t)n_batch * C_ * HW_ * sizeof(float);
  if (ws_size >= need) {
    float* feat_t = (float*)d_ws;
    dim3 tb(256);
    dim3 tg(HW_ / 256, C_ / 16, n_batch);
    hipLaunchKernelGGL(transpose_nchw_nhwc, tg, tb, 0, stream, feat, feat_t);
    hipLaunchKernelGGL(roi_align_rotated_nhwc, dim3(n_rois), dim3(256),
                       0, stream, feat_t, rois, out);
  } else {
    hipLaunchKernelGGL(roi_align_rotated_nchw, dim3(n_rois), dim3(256),
                       0, stream, feat, rois, out);
  }
}

// Round 3
// 323.060 us; speedup vs baseline: 1.1381x; 1.1381x over previous
//
#include <hip/hip_runtime.h>
#include <hip/hip_fp16.h>

#define SPATIAL_SCALE 0.25f
#define PH_ 7
#define PW_ 7
#define NBINS 49
#define NSAMP 196          // 49 bins * 4 samples
#define C_ 256
#define H_ 256
#define W_ 256
#define HW_ (H_ * W_)

// ---------------------------------------------------------------------------
// Transpose NCHW -> NHWC. 64px x 64ch tile through LDS.
// Read:  thread t loads a 4ch x 4px block as 4 float4 (rows = channels),
//        per instruction a wave covers 4 channel rows x 256 B contiguous.
// LDS:   4x4 register transpose, then 4x ds_write_b128 into tile[p][c],
//        row stride 68 floats -> even bank spread both phases.
// Write: thread t reads tile[p][c4..c4+3] as float4 and stores float4 along
//        channels; per instruction a wave covers 4 pixel rows x 256 B.
// ---------------------------------------------------------------------------
__global__ __launch_bounds__(256) void transpose_nchw_nhwc(
    const float* __restrict__ in, float* __restrict__ out) {
  __shared__ float tile[64 * 68];     // [pixel][channel], stride 68
  const int b  = blockIdx.z;
  const int p0 = blockIdx.x * 64;
  const int c0 = blockIdx.y * 64;
  const int t  = threadIdx.x;
  const int i  = t & 15;              // pixel quad index   (x4)
  const int q  = t >> 4;              // channel quad index (x4), 0..15

  const float* src = in + (size_t)b * C_ * HW_ + (size_t)(c0 + 4 * q) * HW_
                        + (p0 + 4 * i);
  const float4 r0 = *(const float4*)(src + 0 * HW_);
  const float4 r1 = *(const float4*)(src + 1 * HW_);
  const float4 r2 = *(const float4*)(src + 2 * HW_);
  const float4 r3 = *(const float4*)(src + 3 * HW_);

  float* tp = &tile[(4 * i) * 68 + 4 * q];
  *(float4*)(tp + 0 * 68) = make_float4(r0.x, r1.x, r2.x, r3.x);
  *(float4*)(tp + 1 * 68) = make_float4(r0.y, r1.y, r2.y, r3.y);
  *(float4*)(tp + 2 * 68) = make_float4(r0.z, r1.z, r2.z, r3.z);
  *(float4*)(tp + 3 * 68) = make_float4(r0.w, r1.w, r2.w, r3.w);
  __syncthreads();

  float* dst = out + (size_t)b * HW_ * C_ + (size_t)(p0 + q) * C_ + (c0 + 4 * i);
#pragma unroll
  for (int k = 0; k < 4; ++k) {
    const float4 v = *(const float4*)&tile[(16 * k + q) * 68 + 4 * i];
    *(float4*)(dst + (size_t)(16 * k) * C_) = v;
  }
}

// ---------------------------------------------------------------------------
// Main NHWC kernel: one block per roi, thread = channel (R1 structure).
// Descriptors packed: int = corner base offset (multiple of C_=256, so low
// bits hold dx/dy step flags); weights as half4, zeroed when sample invalid.
// res[] uses XOR-swizzled columns (no padding) -> 52.5 KB LDS, 3 blocks/CU.
// ---------------------------------------------------------------------------
__global__ __launch_bounds__(256, 3) void roi_align_rotated_nhwc(
    const float* __restrict__ feat, const float* __restrict__ rois,
    float* __restrict__ out) {
  __shared__ int     d_off[NSAMP];        // base | dx(1) | dy(2)
  __shared__ __half2 d_w[NSAMP * 2];      // (w11,w12),(w21,w22)
  __shared__ float   res[NBINS * 256];    // column-swizzled

  const int r = blockIdx.x;
  const int t = threadIdx.x;

  if (t < NSAMP) {
    const float* rp = rois + r * 6;
    const int   b  = (int)rp[0];
    const float cx = rp[1] * SPATIAL_SCALE - 0.5f;
    const float cy = rp[2] * SPATIAL_SCALE - 0.5f;
    const float rw = rp[3] * SPATIAL_SCALE;
    const float rh = rp[4] * SPATIAL_SCALE;
    float sn, cs;
    sincosf(rp[5], &sn, &cs);             // CLOCKWISE=False
    const float bin_h = rh / (float)PH_;
    const float bin_w = rw / (float)PW_;

    const int bin = t >> 2;
    const int sub = t & 3;
    const int ph  = bin / 7;
    const int pw  = bin - ph * 7;
    const int iy  = sub >> 1;
    const int ix  = sub & 1;

    const float yy = -0.5f * rh + ((float)ph + ((float)iy + 0.5f) * 0.5f) * bin_h;
    const float xx = -0.5f * rw + ((float)pw + ((float)ix + 0.5f) * 0.5f) * bin_w;
    float y = yy * cs - xx * sn + cy;
    float x = yy * sn + xx * cs + cx;

    const bool valid = (y > -1.0f) && (y < (float)H_) &&
                       (x > -1.0f) && (x < (float)W_);
    y = fminf(fmaxf(y, 0.0f), (float)(H_ - 1));
    x = fminf(fmaxf(x, 0.0f), (float)(W_ - 1));
    const int yl = (int)y;
    const int xl = (int)x;
    const float ly = y - (float)yl, lx = x - (float)xl;
    const float hy = 1.0f - ly, hx = 1.0f - lx;
    float w11 = hy * hx, w12 = hy * lx, w21 = ly * hx, w22 = ly * lx;
    if (!valid) { w11 = w12 = w21 = w22 = 0.0f; }

    const int base = ((b * H_ + yl) * W_ + xl) * C_;
    const int dxf  = (xl < W_ - 1) ? 1 : 0;
    const int dyf  = (yl < H_ - 1) ? 2 : 0;
    d_off[t]       = base | dxf | dyf;
    d_w[2 * t]     = __floats2half2_rn(w11, w12);
    d_w[2 * t + 1] = __floats2half2_rn(w21, w22);
  }
  __syncthreads();

  const int c = t;
  for (int bin = 0; bin < NBINS; ++bin) {
    float acc = 0.0f;
#pragma unroll
    for (int sub = 0; sub < 4; ++sub) {
      const int s    = bin * 4 + sub;
      const int pc   = d_off[s];
      const int base = (pc & ~255) + c;
      const int dx   = (pc & 1) ? C_ : 0;
      const int dy   = (pc & 2) ? (W_ * C_) : 0;
      const float2 wa = __half22float2(d_w[2 * s]);
      const float2 wb = __half22float2(d_w[2 * s + 1]);
      acc += wa.x * feat[base];
      acc += wa.y * feat[base + dx];
      acc += wb.x * feat[base + dy];
      acc += wb.y * feat[base + dx + dy];
    }
    res[bin * 256 + (c ^ (bin & 31))] = acc * 0.25f;
  }
  __syncthreads();

  // linear (fully coalesced) write of the roi's 49 KB output slab
  float* outr = out + (size_t)r * (C_ * NBINS);
#pragma unroll 1
  for (int i = t; i < C_ * NBINS; i += 256) {
    const int cc = i / NBINS;
    const int bb = i - cc * NBINS;
    outr[i] = res[bb * 256 + (cc ^ (bb & 31))];
  }
}

// ---------------------------------------------------------------------------
// Fallback: direct NCHW (only if ws too small for the transposed copy).
// ---------------------------------------------------------------------------
__global__ __launch_bounds__(256) void roi_align_rotated_nchw(
    const float* __restrict__ feat, const float* __restrict__ rois,
    float* __restrict__ out) {
  __shared__ int   d_pix[NSAMP];          // b*HW + yl*W + xl packed separately
  __shared__ int   d_step[NSAMP];         // dx(1)|dy(2)
  __shared__ float4 d_wt[NSAMP];
  __shared__ float res[NBINS * 257];

  const int r = blockIdx.x;
  const int t = threadIdx.x;
  if (t < NSAMP) {
    const float* rp = rois + r * 6;
    const int   b  = (int)rp[0];
    const float cx = rp[1] * SPATIAL_SCALE - 0.5f;
    const float cy = rp[2] * SPATIAL_SCALE - 0.5f;
    const float rw = rp[3] * SPATIAL_SCALE;
    const float rh = rp[4] * SPATIAL_SCALE;
    float sn, cs;
    sincosf(rp[5], &sn, &cs);
    const float bin_h = rh / (float)PH_;
    const float bin_w = rw / (float)PW_;
    const int bin = t >> 2, sub = t & 3;
    const int ph = bin / 7, pw = bin - ph * 7;
    const int iy = sub >> 1, ix = sub & 1;
    const float yy = -0.5f * rh + ((float)ph + ((float)iy + 0.5f) * 0.5f) * bin_h;
    const float xx = -0.5f * rw + ((float)pw + ((float)ix + 0.5f) * 0.5f) * bin_w;
    float y = yy * cs - xx * sn + cy;
    float x = yy * sn + xx * cs + cx;
    const bool valid = (y > -1.0f) && (y < (float)H_) &&
                       (x > -1.0f) && (x < (float)W_);
    y = fminf(fmaxf(y, 0.0f), (float)(H_ - 1));
    x = fminf(fmaxf(x, 0.0f), (float)(W_ - 1));
    const int yl = (int)y, xl = (int)x;
    const float ly = y - (float)yl, lx = x - (float)xl;
    const float hy = 1.0f - ly, hx = 1.0f - lx;
    float w11 = hy * hx, w12 = hy * lx, w21 = ly * hx, w22 = ly * lx;
    if (!valid) { w11 = w12 = w21 = w22 = 0.0f; }
    d_pix[t]  = (b * H_ + yl) * W_ + xl;
    d_step[t] = ((xl < W_ - 1) ? 1 : 0) | ((yl < H_ - 1) ? 2 : 0);
    d_wt[t]   = make_float4(w11, w12, w21, w22);
  }
  __syncthreads();

  const int c = t;
  const size_t coff = (size_t)c * HW_;
  for (int bin = 0; bin < NBINS; ++bin) {
    float acc = 0.0f;
#pragma unroll
    for (int sub = 0; sub < 4; ++sub) {
      const int s = bin * 4 + sub;
      const int p = d_pix[s];
      const int st = d_step[s];
      const int dx = (st & 1) ? 1 : 0;
      const int dy = (st & 2) ? W_ : 0;
      const float4 w = d_wt[s];
      const int bb = (p / HW_) * C_ * HW_ + (p % HW_);  // expand batch
      acc += w.x * feat[bb + coff];
      acc += w.y * feat[bb + coff + dx];
      acc += w.z * feat[bb + coff + dy];
      acc += w.w * feat[bb + coff + dx + dy];
    }
    res[bin * 257 + c] = acc * 0.25f;
  }
  __syncthreads();
  float* outr = out + (size_t)r * (C_ * NBINS);
#pragma unroll 1
  for (int i = t; i < C_ * NBINS; i += 256) {
    const int cc = i / NBINS;
    const int bb = i - cc * NBINS;
    outr[i] = res[bb * 257 + cc];
  }
}

// ---------------------------------------------------------------------------
extern "C" void kernel_launch(void* const* d_in, const int* in_sizes, int n_in,
                              void* d_out, int out_size, void* d_ws, size_t ws_size,
                              hipStream_t stream) {
  const float* feat = (const float*)d_in[0];
  const float* rois = (const float*)d_in[1];
  float* out = (float*)d_out;
  const int n_rois  = in_sizes[1] / 6;
  const int n_batch = in_sizes[0] / (C_ * HW_);

  const size_t need = (size_t)n_batch * C_ * HW_ * sizeof(float);
  if (ws_size >= need) {
    float* feat_t = (float*)d_ws;
    dim3 tg(HW_ / 64, C_ / 64, n_batch);
    hipLaunchKernelGGL(transpose_nchw_nhwc, tg, dim3(256), 0, stream, feat, feat_t);
    hipLaunchKernelGGL(roi_align_rotated_nhwc, dim3(n_rois), dim3(256),
                       0, stream, feat_t, rois, out);
  } else {
    hipLaunchKernelGGL(roi_align_rotated_nchw, dim3(n_rois), dim3(256),
                       0, stream, feat, rois, out);
  }
}